// Round 6
// baseline (448.271 us; speedup 1.0000x reference)
//
#include <hip/hip_runtime.h>

typedef __attribute__((ext_vector_type(8))) short short8;
typedef __attribute__((ext_vector_type(4))) float f32x4;

#define DIM 1024
#define NH 16
#define HD 64
#define LAT 128
#define QR 256
#define NCAT (LAT + QR) /* 384 */
#define BB 4
#define SS 2048
#define BS (BB * SS) /* 8192 */

// exp(s*0.125) == exp2(s * 0.125*log2(e))
#define SCALE_LOG2E 0.18033688011112042f

__device__ __forceinline__ unsigned short f2b(float f) {
  unsigned int u = __builtin_bit_cast(unsigned int, f);
  u += 0x7FFFu + ((u >> 16) & 1u); // RNE
  return (unsigned short)(u >> 16);
}
__device__ __forceinline__ float b2f(unsigned short h) {
  unsigned int u = ((unsigned int)h) << 16;
  return __builtin_bit_cast(float, u);
}
// pack hi16(f0)|hi16(f1)<<16 with round-half-up (safe: inputs >= 0, no NaN)
__device__ __forceinline__ unsigned int pack_bf16_pair(float f0, float f1) {
  unsigned int u0 = __builtin_bit_cast(unsigned int, f0) + 0x8000u;
  unsigned int u1 = __builtin_bit_cast(unsigned int, f1) + 0x8000u;
  return __builtin_amdgcn_perm(u1, u0, 0x07060302u);
}

__global__ __launch_bounds__(256) void cvt_x(const float* __restrict__ in,
                                             unsigned short* __restrict__ out, int n4) {
  int i = blockIdx.x * 256 + threadIdx.x;
  if (i >= n4) return;
  f32x4 v = ((const f32x4*)in)[i];
  ushort4 o;
  o.x = f2b(v[0]); o.y = f2b(v[1]); o.z = f2b(v[2]); o.w = f2b(v[3]);
  ((ushort4*)out)[i] = o;
}

// Fused prep: all 5 weight transposes (f32 [K][N] -> bf16 [N][K], 64x64 LDS
// tiles) + bias concat, one launch. Block id selects segment (wave-uniform).
__global__ __launch_bounds__(256) void prep_weights(
    const float* __restrict__ w_kvc, const float* __restrict__ w_qc,
    const float* __restrict__ w_kvu, const float* __restrict__ w_qu,
    const float* __restrict__ w_o, const float* __restrict__ b_kvc,
    const float* __restrict__ b_qc, unsigned short* __restrict__ wcatT,
    unsigned short* __restrict__ wkvuT, unsigned short* __restrict__ wquT,
    unsigned short* __restrict__ woT, float* __restrict__ bias_cat) {
  __shared__ unsigned short T[64 * 72];
  const int id = blockIdx.x;
  const int tid = threadIdx.x;
  if (id >= 480) { // bias concat (384 floats)
    if (tid < LAT) bias_cat[tid] = b_kvc[tid];
    else bias_cat[tid] = b_qc[tid - LAT];
    if (tid < 128) bias_cat[tid + 256] = b_qc[tid + 128];
    return;
  }
  const float* in; unsigned short* out; int K, N, tile;
  if (id < 32)       { in = w_kvc; out = wcatT;                       K = DIM; N = LAT;     tile = id; }
  else if (id < 96)  { in = w_qc;  out = wcatT + (size_t)LAT * DIM;   K = DIM; N = QR;      tile = id - 32; }
  else if (id < 160) { in = w_kvu; out = wkvuT;                       K = LAT; N = 2 * DIM; tile = id - 96; }
  else if (id < 224) { in = w_qu;  out = wquT;                        K = QR;  N = DIM;     tile = id - 160; }
  else               { in = w_o;   out = woT;                         K = DIM; N = DIM;     tile = id - 224; }
  const int ktiles = K >> 6;
  const int k0 = (tile % ktiles) * 64, n0 = (tile / ktiles) * 64;
  {
    const int r = tid >> 2, cq = (tid & 3) * 16;
#pragma unroll
    for (int j = 0; j < 4; ++j) {
      f32x4 v = *(const f32x4*)(in + (size_t)(k0 + r) * N + n0 + cq + j * 4);
      ushort4 o;
      o.x = f2b(v[0]); o.y = f2b(v[1]); o.z = f2b(v[2]); o.w = f2b(v[3]);
      *(ushort4*)(T + r * 72 + cq + j * 4) = o;
    }
  }
  __syncthreads();
#pragma unroll
  for (int s = 0; s < 2; ++s) {
    int idx = tid + s * 256;
    int nr = idx >> 3, kg = (idx & 7) * 8;
    short8 o;
#pragma unroll
    for (int i = 0; i < 8; i++) o[i] = T[(kg + i) * 72 + nr];
    *(short8*)(out + (size_t)(n0 + nr) * K + k0 + kg) = o;
  }
}

// V (cols DIM..2*DIM of kvup) -> VT[b][d][s]  (bf16)
__global__ __launch_bounds__(256) void transpose_v(const unsigned short* __restrict__ KVb,
                                                   unsigned short* __restrict__ VTb) {
  __shared__ unsigned short T[64 * 72];
  const int tid = threadIdx.x;
  const int st = blockIdx.x, dt = blockIdx.y, b = blockIdx.z;
  const int s0 = st * 64, d0 = dt * 64;
#pragma unroll
  for (int t = 0; t < 2; ++t) {
    int idx = tid + t * 256;
    int r = idx >> 3, c = idx & 7;
    short8 v = *(const short8*)(KVb + (size_t)(b * SS + s0 + r) * (2 * DIM) + DIM + d0 + c * 8);
    *(short8*)(T + r * 72 + c * 8) = v;
  }
  __syncthreads();
#pragma unroll
  for (int t = 0; t < 2; ++t) {
    int idx = tid + t * 256;
    int dr = idx >> 3, cg = idx & 7;
    short8 o;
#pragma unroll
    for (int i = 0; i < 8; i++) o[i] = T[(cg * 8 + i) * 72 + dr];
    *(short8*)(VTb + (size_t)(b * DIM + d0 + dr) * SS + s0 + cg * 8) = o;
  }
}

// C[M,N] = A[M,K](bf16, row stride lda) @ WT[N,K](bf16) + bias; 64x64/wave,
// 128x128/block. K-loop software-pipelined (ping-pong frag sets, K mult of 64).
__global__ __launch_bounds__(256) void gemm_bf16(const unsigned short* __restrict__ A,
                                                 const unsigned short* __restrict__ WT,
                                                 const float* __restrict__ bias,
                                                 float* __restrict__ outF,
                                                 unsigned short* __restrict__ outB,
                                                 int N, int K, int lda, int ldout) {
  const int tid = threadIdx.x;
  const int wave = tid >> 6, lane = tid & 63;
  const int ln = lane & 15, quad = lane >> 4;
  const int m0 = blockIdx.x * 128 + (wave >> 1) * 64;
  const int n0 = blockIdx.y * 128 + (wave & 1) * 64;

  f32x4 acc[4][4];
#pragma unroll
  for (int i = 0; i < 4; i++)
#pragma unroll
    for (int j = 0; j < 4; j++) acc[i][j] = (f32x4){0.f, 0.f, 0.f, 0.f};

  const unsigned short* Ap = A + (size_t)(m0 + ln) * lda + quad * 8;
  const unsigned short* Wp = WT + (size_t)(n0 + ln) * K + quad * 8;

  short8 aA[4], bA[4], aB[4], bB[4];
#pragma unroll
  for (int i = 0; i < 4; i++) {
    aA[i] = *(const short8*)(Ap + (size_t)i * 16 * lda);
    bA[i] = *(const short8*)(Wp + (size_t)i * 16 * K);
  }
  for (int k0 = 0; k0 < K; k0 += 64) {
    const bool hasB = (k0 + 32 < K);
    if (hasB) {
#pragma unroll
      for (int i = 0; i < 4; i++) {
        aB[i] = *(const short8*)(Ap + (size_t)i * 16 * lda + k0 + 32);
        bB[i] = *(const short8*)(Wp + (size_t)i * 16 * K + k0 + 32);
      }
    }
#pragma unroll
    for (int mi = 0; mi < 4; mi++)
#pragma unroll
      for (int ni = 0; ni < 4; ni++)
        acc[mi][ni] =
            __builtin_amdgcn_mfma_f32_16x16x32_bf16(aA[mi], bA[ni], acc[mi][ni], 0, 0, 0);
    if (k0 + 64 < K) {
#pragma unroll
      for (int i = 0; i < 4; i++) {
        aA[i] = *(const short8*)(Ap + (size_t)i * 16 * lda + k0 + 64);
        bA[i] = *(const short8*)(Wp + (size_t)i * 16 * K + k0 + 64);
      }
    }
    if (hasB) {
#pragma unroll
      for (int mi = 0; mi < 4; mi++)
#pragma unroll
        for (int ni = 0; ni < 4; ni++)
          acc[mi][ni] =
              __builtin_amdgcn_mfma_f32_16x16x32_bf16(aB[mi], bB[ni], acc[mi][ni], 0, 0, 0);
    }
  }

#pragma unroll
  for (int mi = 0; mi < 4; mi++) {
    const int row = m0 + mi * 16 + quad * 4;
#pragma unroll
    for (int ni = 0; ni < 4; ni++) {
      const int col = n0 + ni * 16 + ln;
      const float bv = bias[col];
#pragma unroll
      for (int r = 0; r < 4; r++) {
        float v = acc[mi][ni][r] + bv;
        size_t o = (size_t)(row + r) * ldout + col;
        if (outF) outF[o] = v;
        if (outB) outB[o] = f2b(v);
      }
    }
  }
}

// Small-N GEMM: 64x64/block, 32x32/wave; K-loop software-pipelined.
__global__ __launch_bounds__(256) void gemm_n64(const unsigned short* __restrict__ A,
                                                const unsigned short* __restrict__ WT,
                                                const float* __restrict__ bias,
                                                unsigned short* __restrict__ outB,
                                                int K, int ldout) {
  const int tid = threadIdx.x;
  const int wave = tid >> 6, lane = tid & 63;
  const int ln = lane & 15, quad = lane >> 4;
  const int m0 = blockIdx.x * 64 + (wave >> 1) * 32;
  const int n0 = blockIdx.y * 64 + (wave & 1) * 32;

  f32x4 acc[2][2];
#pragma unroll
  for (int i = 0; i < 2; i++)
#pragma unroll
    for (int j = 0; j < 2; j++) acc[i][j] = (f32x4){0.f, 0.f, 0.f, 0.f};

  const unsigned short* Ap = A + (size_t)(m0 + ln) * K + quad * 8;
  const unsigned short* Wp = WT + (size_t)(n0 + ln) * K + quad * 8;

  short8 aA[2], bA[2], aB[2], bB[2];
#pragma unroll
  for (int i = 0; i < 2; i++) {
    aA[i] = *(const short8*)(Ap + (size_t)i * 16 * K);
    bA[i] = *(const short8*)(Wp + (size_t)i * 16 * K);
  }
  for (int k0 = 0; k0 < K; k0 += 64) {
    const bool hasB = (k0 + 32 < K);
    if (hasB) {
#pragma unroll
      for (int i = 0; i < 2; i++) {
        aB[i] = *(const short8*)(Ap + (size_t)i * 16 * K + k0 + 32);
        bB[i] = *(const short8*)(Wp + (size_t)i * 16 * K + k0 + 32);
      }
    }
#pragma unroll
    for (int mi = 0; mi < 2; mi++)
#pragma unroll
      for (int ni = 0; ni < 2; ni++)
        acc[mi][ni] =
            __builtin_amdgcn_mfma_f32_16x16x32_bf16(aA[mi], bA[ni], acc[mi][ni], 0, 0, 0);
    if (k0 + 64 < K) {
#pragma unroll
      for (int i = 0; i < 2; i++) {
        aA[i] = *(const short8*)(Ap + (size_t)i * 16 * K + k0 + 64);
        bA[i] = *(const short8*)(Wp + (size_t)i * 16 * K + k0 + 64);
      }
    }
    if (hasB) {
#pragma unroll
      for (int mi = 0; mi < 2; mi++)
#pragma unroll
        for (int ni = 0; ni < 2; ni++)
          acc[mi][ni] =
              __builtin_amdgcn_mfma_f32_16x16x32_bf16(aB[mi], bB[ni], acc[mi][ni], 0, 0, 0);
    }
  }

#pragma unroll
  for (int mi = 0; mi < 2; mi++) {
    const int row = m0 + mi * 16 + quad * 4;
#pragma unroll
    for (int ni = 0; ni < 2; ni++) {
      const int col = n0 + ni * 16 + ln;
      const float bv = bias[col];
#pragma unroll
      for (int r = 0; r < 4; r++)
        outB[(size_t)(row + r) * ldout + col] = f2b(acc[mi][ni][r] + bv);
    }
  }
}

// MFMA flash attention, causal, fixed-max softmax, S^T orientation, with
// single-barrier double-buffered K/V staging:
//   iter kt: barrier; write buf[(kt+1)%2] from prefetched regs (overlaps other
//   waves' compute); prefetch kt+2; compute from buf[kt%2].
// S^T = K.Q^T (A=K-frag, B=Q-frag): C col=q(ln), row=key(quad*4+r) -> P packs
// as b64 per nt (v_perm pair-pack, round-half-up), denom is one scalar/thread.
// PV: A=P[q][key], B=V^T[d][key] -> D[q][d]. LDS rows padded to 72 shorts.
__global__ __launch_bounds__(256) void attn_mfma(const unsigned short* __restrict__ Qb,
                                                 const unsigned short* __restrict__ KVb,
                                                 const unsigned short* __restrict__ VTb,
                                                 unsigned short* __restrict__ ctxB) {
  __shared__ unsigned short smem[2 * 2 * 64 * 72 + 4 * 16 * 72]; // 46080 B
  unsigned short* Ps = smem + 4 * 64 * 72;
  const int tid = threadIdx.x;
  const int wave = tid >> 6, lane = tid & 63;
  const int ln = lane & 15, quad = lane >> 4;
  const int qt = (gridDim.x - 1) - blockIdx.x; // big blocks launch first
  const int h = blockIdx.y, b = blockIdx.z;
  const int s0 = qt * 64;

  short8 qfrag[2]; // B-operand: rows = q (wave*16+ln)
  {
    const unsigned short* qp =
        Qb + (size_t)(b * SS + s0 + wave * 16 + ln) * DIM + h * HD + quad * 8;
    qfrag[0] = *(const short8*)qp;
    qfrag[1] = *(const short8*)(qp + 32);
  }

  f32x4 octx[4]; // PV acc: row q=quad*4+r (in wave tile), col d=dt*16+ln
  float lpart = 0.f; // partial denom for q=ln
#pragma unroll
  for (int i = 0; i < 4; i++) octx[i] = (f32x4){0.f, 0.f, 0.f, 0.f};

  unsigned short* Pw = Ps + wave * (16 * 72);
  const int srow = tid >> 3, sc8 = (tid & 7) * 8;

  // running staging pointers (advance by constant per K-tile)
  const unsigned short* kptr =
      KVb + (size_t)(b * SS + srow) * (2 * DIM) + h * HD + sc8;
  const unsigned short* vptr = VTb + (size_t)(b * DIM + h * HD + srow) * SS + sc8;
  const size_t kstep = (size_t)64 * 2 * DIM; // 64 key-rows
  const size_t vstep = 64;                   // 64 key-cols

  short8 kreg[2], vreg[2];
#pragma unroll
  for (int t = 0; t < 2; ++t) {
    kreg[t] = *(const short8*)(kptr + (size_t)t * 32 * 2 * DIM);
    vreg[t] = *(const short8*)(vptr + (size_t)t * 32 * SS);
  }
  // prologue: fill buf0 (no prior readers), prefetch tile 1
  {
    unsigned short* K0 = smem;
    unsigned short* V0 = smem + 4608;
#pragma unroll
    for (int t = 0; t < 2; ++t) {
      *(short8*)(K0 + (srow + t * 32) * 72 + sc8) = kreg[t];
      *(short8*)(V0 + (srow + t * 32) * 72 + sc8) = vreg[t];
    }
  }
  if (qt >= 1) {
    kptr += kstep; vptr += vstep;
#pragma unroll
    for (int t = 0; t < 2; ++t) {
      kreg[t] = *(const short8*)(kptr + (size_t)t * 32 * 2 * DIM);
      vreg[t] = *(const short8*)(vptr + (size_t)t * 32 * SS);
    }
  }

  for (int kt = 0; kt <= qt; ++kt) {
    __syncthreads(); // buf[kt%2] writes visible; prior readers of buf[(kt+1)%2] done
    if (kt < qt) { // stage tile kt+1 into the other buffer
      unsigned short* Kn = smem + ((kt + 1) & 1) * 9216;
      unsigned short* Vn = Kn + 4608;
#pragma unroll
      for (int t = 0; t < 2; ++t) {
        *(short8*)(Kn + (srow + t * 32) * 72 + sc8) = kreg[t];
        *(short8*)(Vn + (srow + t * 32) * 72 + sc8) = vreg[t];
      }
      if (kt + 1 < qt) { // prefetch tile kt+2
        kptr += kstep; vptr += vstep;
#pragma unroll
        for (int t = 0; t < 2; ++t) {
          kreg[t] = *(const short8*)(kptr + (size_t)t * 32 * 2 * DIM);
          vreg[t] = *(const short8*)(vptr + (size_t)t * 32 * SS);
        }
      }
    }

    const unsigned short* Ksb = smem + (kt & 1) * 9216;
    const unsigned short* Vtsb = Ksb + 4608;
    const bool diag = (kt == qt);

    f32x4 sacc[4]; // S^T: nt -> keys nt*16+quad*4+r, col q=ln
#pragma unroll
    for (int nt = 0; nt < 4; nt++) sacc[nt] = (f32x4){0.f, 0.f, 0.f, 0.f};
#pragma unroll
    for (int kc = 0; kc < 2; kc++) {
#pragma unroll
      for (int nt = 0; nt < 4; nt++) {
        if (diag && nt > wave) continue; // fully-masked key strip for this wave
        short8 kfrag = *(const short8*)(Ksb + (nt * 16 + ln) * 72 + kc * 32 + quad * 8);
        sacc[nt] =
            __builtin_amdgcn_mfma_f32_16x16x32_bf16(kfrag, qfrag[kc], sacc[nt], 0, 0, 0);
      }
    }

    // Fixed-max softmax (elementwise); perm-packed b64 P-writes.
    const int qg_rel = wave * 16 + ln;
#pragma unroll
    for (int nt = 0; nt < 4; nt++) {
      float pe[4];
#pragma unroll
      for (int r = 0; r < 4; r++) {
        float p = __builtin_exp2f(sacc[nt][r] * SCALE_LOG2E);
        if (diag && (nt * 16 + quad * 4 + r) > qg_rel) p = 0.f;
        lpart += p;
        pe[r] = p;
      }
      uint2 pw;
      pw.x = pack_bf16_pair(pe[0], pe[1]);
      pw.y = pack_bf16_pair(pe[2], pe[3]);
      *(uint2*)(Pw + ln * 72 + nt * 16 + quad * 4) = pw;
    }

#pragma unroll
    for (int kc = 0; kc < 2; kc++) {
      if (diag && kc == 1 && wave < 2) continue; // P cols 32..63 all zero
      short8 pfrag = *(const short8*)(Pw + ln * 72 + kc * 32 + quad * 8);
#pragma unroll
      for (int dt = 0; dt < 4; dt++) {
        short8 vfrag = *(const short8*)(Vtsb + (dt * 16 + ln) * 72 + kc * 32 + quad * 8);
        octx[dt] =
            __builtin_amdgcn_mfma_f32_16x16x32_bf16(pfrag, vfrag, octx[dt], 0, 0, 0);
      }
    }
  }

  // Denominator: reduce across the 4 quads, broadcast to owned rows.
  lpart += __shfl_xor(lpart, 16, 64);
  lpart += __shfl_xor(lpart, 32, 64);
  float linv[4];
#pragma unroll
  for (int r = 0; r < 4; r++) linv[r] = 1.f / __shfl(lpart, quad * 4 + r, 64);

  // Epilogue: normalize, stage through smem, coalesced 16B stores.
  __syncthreads();
#pragma unroll
  for (int r = 0; r < 4; r++) {
#pragma unroll
    for (int dt = 0; dt < 4; dt++)
      smem[(wave * 16 + quad * 4 + r) * 72 + dt * 16 + ln] = f2b(octx[dt][r] * linv[r]);
  }
  __syncthreads();
#pragma unroll
  for (int t = 0; t < 2; ++t) {
    int idx = tid + t * 256;
    int row = idx >> 3, c = idx & 7;
    short8 v = *(const short8*)(smem + row * 72 + c * 8);
    *(short8*)(ctxB + (size_t)(b * SS + s0 + row) * DIM + h * HD + c * 8) = v;
  }
}

extern "C" void kernel_launch(void* const* d_in, const int* in_sizes, int n_in,
                              void* d_out, int out_size, void* d_ws, size_t ws_size,
                              hipStream_t stream) {
  const float* x     = (const float*)d_in[0];
  const float* w_kvc = (const float*)d_in[2];
  const float* b_kvc = (const float*)d_in[3];
  const float* w_kvu = (const float*)d_in[4];
  const float* b_kvu = (const float*)d_in[5];
  const float* w_qc  = (const float*)d_in[6];
  const float* b_qc  = (const float*)d_in[7];
  const float* w_qu  = (const float*)d_in[8];
  const float* b_qu  = (const float*)d_in[9];
  const float* w_o   = (const float*)d_in[10];
  const float* b_o   = (const float*)d_in[11];
  float* out = (float*)d_out;

  unsigned short* xb     = (unsigned short*)d_ws;          // [BS][DIM]; reused as VT
  unsigned short* wcatT  = xb + (size_t)BS * DIM;          // [NCAT][DIM]
  unsigned short* wkvuT  = wcatT + (size_t)NCAT * DIM;     // [2*DIM][LAT]
  unsigned short* wquT   = wkvuT + (size_t)LAT * 2 * DIM;  // [DIM][QR]
  unsigned short* woT    = wquT + (size_t)QR * DIM;        // [DIM][DIM]
  unsigned short* kvqlat = woT + (size_t)DIM * DIM;        // [BS][NCAT] (kv | q)
  unsigned short* kvup   = kvqlat + (size_t)BS * NCAT;     // [BS][2*DIM] (K | V)
  unsigned short* Qbuf   = kvup + (size_t)BS * 2 * DIM;    // [BS][DIM]
  unsigned short* ctx    = Qbuf + (size_t)BS * DIM;        // [BS][DIM]
  float* bias_cat        = (float*)(ctx + (size_t)BS * DIM); // [NCAT]

  cvt_x<<<(BS * DIM / 4 + 255) / 256, 256, 0, stream>>>(x, xb, BS * DIM / 4);
  prep_weights<<<481, 256, 0, stream>>>(w_kvc, w_qc, w_kvu, w_qu, w_o, b_kvc, b_qc,
                                        wcatT, wkvuT, wquT, woT, bias_cat);

  // fused stage-1: [kvlat | qlat] = x @ [w_kvc | w_qc]
  gemm_n64<<<dim3(BS / 64, NCAT / 64), 256, 0, stream>>>(xb, wcatT, bias_cat, kvqlat,
                                                         DIM, NCAT);
  // stage-2
  gemm_bf16<<<dim3(BS / 128, 2 * DIM / 128), 256, 0, stream>>>(
      kvqlat, wkvuT, b_kvu, nullptr, kvup, 2 * DIM, LAT, NCAT, 2 * DIM);
  unsigned short* VT = xb; // xb dead after stage-1
  transpose_v<<<dim3(SS / 64, DIM / 64, BB), 256, 0, stream>>>(kvup, VT);
  gemm_bf16<<<dim3(BS / 128, DIM / 128), 256, 0, stream>>>(
      kvqlat + LAT, wquT, b_qu, nullptr, Qbuf, DIM, QR, NCAT, DIM);
  attn_mfma<<<dim3(SS / 64, NH, BB), 256, 0, stream>>>(Qbuf, kvup, VT, ctx);
  gemm_bf16<<<dim3(BS / 128, DIM / 128), 256, 0, stream>>>(ctx, woT, b_o, out, nullptr,
                                                           DIM, DIM, DIM, DIM);
}

// Round 7
// 414.380 us; speedup vs baseline: 1.0818x; 1.0818x over previous
//
#include <hip/hip_runtime.h>

typedef __attribute__((ext_vector_type(8))) short short8;
typedef __attribute__((ext_vector_type(4))) float f32x4;

#define DIM 1024
#define NH 16
#define HD 64
#define LAT 128
#define QR 256
#define NCAT (LAT + QR) /* 384 */
#define BB 4
#define SS 2048
#define BS (BB * SS) /* 8192 */

// exp(s*0.125) == exp2(s * 0.125*log2(e))
#define SCALE_LOG2E 0.18033688011112042f

__device__ __forceinline__ unsigned short f2b(float f) {
  unsigned int u = __builtin_bit_cast(unsigned int, f);
  u += 0x7FFFu + ((u >> 16) & 1u); // RNE
  return (unsigned short)(u >> 16);
}
__device__ __forceinline__ float b2f(unsigned short h) {
  unsigned int u = ((unsigned int)h) << 16;
  return __builtin_bit_cast(float, u);
}
// pack hi16(f0)|hi16(f1)<<16 with round-half-up (safe: inputs >= 0, no NaN)
__device__ __forceinline__ unsigned int pack_bf16_pair(float f0, float f1) {
  unsigned int u0 = __builtin_bit_cast(unsigned int, f0) + 0x8000u;
  unsigned int u1 = __builtin_bit_cast(unsigned int, f1) + 0x8000u;
  return __builtin_amdgcn_perm(u1, u0, 0x07060302u);
}

__global__ __launch_bounds__(256) void cvt_x(const float* __restrict__ in,
                                             unsigned short* __restrict__ out, int n4) {
  int i = blockIdx.x * 256 + threadIdx.x;
  if (i >= n4) return;
  f32x4 v = ((const f32x4*)in)[i];
  ushort4 o;
  o.x = f2b(v[0]); o.y = f2b(v[1]); o.z = f2b(v[2]); o.w = f2b(v[3]);
  ((ushort4*)out)[i] = o;
}

// Fused prep: all 5 weight transposes (f32 [K][N] -> bf16 [N][K], 64x64 LDS
// tiles) + bias concat, one launch.
__global__ __launch_bounds__(256) void prep_weights(
    const float* __restrict__ w_kvc, const float* __restrict__ w_qc,
    const float* __restrict__ w_kvu, const float* __restrict__ w_qu,
    const float* __restrict__ w_o, const float* __restrict__ b_kvc,
    const float* __restrict__ b_qc, unsigned short* __restrict__ wcatT,
    unsigned short* __restrict__ wkvuT, unsigned short* __restrict__ wquT,
    unsigned short* __restrict__ woT, float* __restrict__ bias_cat) {
  __shared__ unsigned short T[64 * 72];
  const int id = blockIdx.x;
  const int tid = threadIdx.x;
  if (id >= 480) { // bias concat (384 floats)
    if (tid < LAT) bias_cat[tid] = b_kvc[tid];
    else bias_cat[tid] = b_qc[tid - LAT];
    if (tid < 128) bias_cat[tid + 256] = b_qc[tid + 128];
    return;
  }
  const float* in; unsigned short* out; int K, N, tile;
  if (id < 32)       { in = w_kvc; out = wcatT;                       K = DIM; N = LAT;     tile = id; }
  else if (id < 96)  { in = w_qc;  out = wcatT + (size_t)LAT * DIM;   K = DIM; N = QR;      tile = id - 32; }
  else if (id < 160) { in = w_kvu; out = wkvuT;                       K = LAT; N = 2 * DIM; tile = id - 96; }
  else if (id < 224) { in = w_qu;  out = wquT;                        K = QR;  N = DIM;     tile = id - 160; }
  else               { in = w_o;   out = woT;                         K = DIM; N = DIM;     tile = id - 224; }
  const int ktiles = K >> 6;
  const int k0 = (tile % ktiles) * 64, n0 = (tile / ktiles) * 64;
  {
    const int r = tid >> 2, cq = (tid & 3) * 16;
#pragma unroll
    for (int j = 0; j < 4; ++j) {
      f32x4 v = *(const f32x4*)(in + (size_t)(k0 + r) * N + n0 + cq + j * 4);
      ushort4 o;
      o.x = f2b(v[0]); o.y = f2b(v[1]); o.z = f2b(v[2]); o.w = f2b(v[3]);
      *(ushort4*)(T + r * 72 + cq + j * 4) = o;
    }
  }
  __syncthreads();
#pragma unroll
  for (int s = 0; s < 2; ++s) {
    int idx = tid + s * 256;
    int nr = idx >> 3, kg = (idx & 7) * 8;
    short8 o;
#pragma unroll
    for (int i = 0; i < 8; i++) o[i] = T[(kg + i) * 72 + nr];
    *(short8*)(out + (size_t)(n0 + nr) * K + k0 + kg) = o;
  }
}

// V (cols DIM..2*DIM of kvup) -> VT[b][d][s]  (bf16)
__global__ __launch_bounds__(256) void transpose_v(const unsigned short* __restrict__ KVb,
                                                   unsigned short* __restrict__ VTb) {
  __shared__ unsigned short T[64 * 72];
  const int tid = threadIdx.x;
  const int st = blockIdx.x, dt = blockIdx.y, b = blockIdx.z;
  const int s0 = st * 64, d0 = dt * 64;
#pragma unroll
  for (int t = 0; t < 2; ++t) {
    int idx = tid + t * 256;
    int r = idx >> 3, c = idx & 7;
    short8 v = *(const short8*)(KVb + (size_t)(b * SS + s0 + r) * (2 * DIM) + DIM + d0 + c * 8);
    *(short8*)(T + r * 72 + c * 8) = v;
  }
  __syncthreads();
#pragma unroll
  for (int t = 0; t < 2; ++t) {
    int idx = tid + t * 256;
    int dr = idx >> 3, cg = idx & 7;
    short8 o;
#pragma unroll
    for (int i = 0; i < 8; i++) o[i] = T[(cg * 8 + i) * 72 + dr];
    *(short8*)(VTb + (size_t)(b * DIM + d0 + dr) * SS + s0 + cg * 8) = o;
  }
}

// C[M,N] = A[M,K](bf16, row stride lda) @ WT[N,K](bf16) + bias; 64x64/wave,
// 128x128/block. K-loop software-pipelined (ping-pong frag sets).
__global__ __launch_bounds__(256) void gemm_bf16(const unsigned short* __restrict__ A,
                                                 const unsigned short* __restrict__ WT,
                                                 const float* __restrict__ bias,
                                                 float* __restrict__ outF,
                                                 unsigned short* __restrict__ outB,
                                                 int N, int K, int lda, int ldout) {
  const int tid = threadIdx.x;
  const int wave = tid >> 6, lane = tid & 63;
  const int ln = lane & 15, quad = lane >> 4;
  const int m0 = blockIdx.x * 128 + (wave >> 1) * 64;
  const int n0 = blockIdx.y * 128 + (wave & 1) * 64;

  f32x4 acc[4][4];
#pragma unroll
  for (int i = 0; i < 4; i++)
#pragma unroll
    for (int j = 0; j < 4; j++) acc[i][j] = (f32x4){0.f, 0.f, 0.f, 0.f};

  const unsigned short* Ap = A + (size_t)(m0 + ln) * lda + quad * 8;
  const unsigned short* Wp = WT + (size_t)(n0 + ln) * K + quad * 8;

  short8 aA[4], bA[4], aB[4], bB[4];
#pragma unroll
  for (int i = 0; i < 4; i++) {
    aA[i] = *(const short8*)(Ap + (size_t)i * 16 * lda);
    bA[i] = *(const short8*)(Wp + (size_t)i * 16 * K);
  }
  for (int k0 = 0; k0 < K; k0 += 64) {
    const bool hasB = (k0 + 32 < K);
    if (hasB) {
#pragma unroll
      for (int i = 0; i < 4; i++) {
        aB[i] = *(const short8*)(Ap + (size_t)i * 16 * lda + k0 + 32);
        bB[i] = *(const short8*)(Wp + (size_t)i * 16 * K + k0 + 32);
      }
    }
#pragma unroll
    for (int mi = 0; mi < 4; mi++)
#pragma unroll
      for (int ni = 0; ni < 4; ni++)
        acc[mi][ni] =
            __builtin_amdgcn_mfma_f32_16x16x32_bf16(aA[mi], bA[ni], acc[mi][ni], 0, 0, 0);
    if (k0 + 64 < K) {
#pragma unroll
      for (int i = 0; i < 4; i++) {
        aA[i] = *(const short8*)(Ap + (size_t)i * 16 * lda + k0 + 64);
        bA[i] = *(const short8*)(Wp + (size_t)i * 16 * K + k0 + 64);
      }
    }
    if (hasB) {
#pragma unroll
      for (int mi = 0; mi < 4; mi++)
#pragma unroll
        for (int ni = 0; ni < 4; ni++)
          acc[mi][ni] =
              __builtin_amdgcn_mfma_f32_16x16x32_bf16(aB[mi], bB[ni], acc[mi][ni], 0, 0, 0);
    }
  }

#pragma unroll
  for (int mi = 0; mi < 4; mi++) {
    const int row = m0 + mi * 16 + quad * 4;
#pragma unroll
    for (int ni = 0; ni < 4; ni++) {
      const int col = n0 + ni * 16 + ln;
      const float bv = bias[col];
#pragma unroll
      for (int r = 0; r < 4; r++) {
        float v = acc[mi][ni][r] + bv;
        size_t o = (size_t)(row + r) * ldout + col;
        if (outF) outF[o] = v;
        if (outB) outB[o] = f2b(v);
      }
    }
  }
}

// Small-N GEMM: 64x64/block, 32x32/wave; K-loop software-pipelined.
__global__ __launch_bounds__(256) void gemm_n64(const unsigned short* __restrict__ A,
                                                const unsigned short* __restrict__ WT,
                                                const float* __restrict__ bias,
                                                unsigned short* __restrict__ outB,
                                                int K, int ldout) {
  const int tid = threadIdx.x;
  const int wave = tid >> 6, lane = tid & 63;
  const int ln = lane & 15, quad = lane >> 4;
  const int m0 = blockIdx.x * 64 + (wave >> 1) * 32;
  const int n0 = blockIdx.y * 64 + (wave & 1) * 32;

  f32x4 acc[2][2];
#pragma unroll
  for (int i = 0; i < 2; i++)
#pragma unroll
    for (int j = 0; j < 2; j++) acc[i][j] = (f32x4){0.f, 0.f, 0.f, 0.f};

  const unsigned short* Ap = A + (size_t)(m0 + ln) * K + quad * 8;
  const unsigned short* Wp = WT + (size_t)(n0 + ln) * K + quad * 8;

  short8 aA[2], bA[2], aB[2], bB[2];
#pragma unroll
  for (int i = 0; i < 2; i++) {
    aA[i] = *(const short8*)(Ap + (size_t)i * 16 * K);
    bA[i] = *(const short8*)(Wp + (size_t)i * 16 * K);
  }
  for (int k0 = 0; k0 < K; k0 += 64) {
    const bool hasB = (k0 + 32 < K);
    if (hasB) {
#pragma unroll
      for (int i = 0; i < 2; i++) {
        aB[i] = *(const short8*)(Ap + (size_t)i * 16 * K + k0 + 32);
        bB[i] = *(const short8*)(Wp + (size_t)i * 16 * K + k0 + 32);
      }
    }
#pragma unroll
    for (int mi = 0; mi < 2; mi++)
#pragma unroll
      for (int ni = 0; ni < 2; ni++)
        acc[mi][ni] =
            __builtin_amdgcn_mfma_f32_16x16x32_bf16(aA[mi], bA[ni], acc[mi][ni], 0, 0, 0);
    if (k0 + 64 < K) {
#pragma unroll
      for (int i = 0; i < 2; i++) {
        aA[i] = *(const short8*)(Ap + (size_t)i * 16 * K + k0 + 64);
        bA[i] = *(const short8*)(Wp + (size_t)i * 16 * K + k0 + 64);
      }
    }
    if (hasB) {
#pragma unroll
      for (int mi = 0; mi < 2; mi++)
#pragma unroll
        for (int ni = 0; ni < 2; ni++)
          acc[mi][ni] =
              __builtin_amdgcn_mfma_f32_16x16x32_bf16(aB[mi], bB[ni], acc[mi][ni], 0, 0, 0);
    }
  }

#pragma unroll
  for (int mi = 0; mi < 2; mi++) {
    const int row = m0 + mi * 16 + quad * 4;
#pragma unroll
    for (int ni = 0; ni < 2; ni++) {
      const int col = n0 + ni * 16 + ln;
      const float bv = bias[col];
#pragma unroll
      for (int r = 0; r < 4; r++)
        outB[(size_t)(row + r) * ldout + col] = f2b(acc[mi][ni][r] + bv);
    }
  }
}

// MFMA flash attention, causal, fixed-max softmax, S^T orientation.
// Block = 128 q-rows x (head,batch), 512 threads = 8 waves; wave w owns q rows
// [s0+w*16, s0+(w+1)*16). One staged 64-key K/V tile + barrier pair serves all
// 128 q-rows (2x barrier amortization vs 64-row blocks at the same wave count).
// Single-buffer staging (R5 structure: sync; write; sync; prefetch; compute).
// S^T = K.Q^T: C col=q(ln), row=key(quad*4+r) -> P packs as b64 (v_perm),
// denom = one scalar/thread. PV: A=P[q][key], B=V^T[d][key] -> D[q][d].
// LDS rows padded to 72 shorts. 36864 B total -> 4 blocks/CU ceiling.
__global__ __launch_bounds__(512) void attn_mfma(const unsigned short* __restrict__ Qb,
                                                 const unsigned short* __restrict__ KVb,
                                                 const unsigned short* __restrict__ VTb,
                                                 unsigned short* __restrict__ ctxB) {
  __shared__ unsigned short smem[(64 + 64) * 72 + 8 * 16 * 72]; // 36864 B
  unsigned short* Ks = smem;              // K tile [key][d]
  unsigned short* Vts = smem + 64 * 72;   // V^T tile [d][key]
  unsigned short* Ps = smem + 128 * 72;   // per-wave P [16 q][key]
  const int tid = threadIdx.x;
  const int wave = tid >> 6, lane = tid & 63;
  const int ln = lane & 15, quad = lane >> 4;
  const int qt = (gridDim.x - 1) - blockIdx.x; // big blocks launch first
  const int h = blockIdx.y, b = blockIdx.z;
  const int s0 = qt * 128;
  const int ktmax = 2 * qt + 1; // inclusive
  const int qmaxw = s0 + wave * 16 + 15; // last q row this wave owns
  const int qminw = s0 + wave * 16;

  short8 qfrag[2]; // B-operand: rows = q (s0 + wave*16 + ln)
  {
    const unsigned short* qp =
        Qb + (size_t)(b * SS + s0 + wave * 16 + ln) * DIM + h * HD + quad * 8;
    qfrag[0] = *(const short8*)qp;
    qfrag[1] = *(const short8*)(qp + 32);
  }

  f32x4 octx[4]; // PV acc: row q=quad*4+r (wave tile), col d=dt*16+ln
  float lpart = 0.f;
#pragma unroll
  for (int i = 0; i < 4; i++) octx[i] = (f32x4){0.f, 0.f, 0.f, 0.f};

  unsigned short* Pw = Ps + wave * (16 * 72);
  const int srow = tid >> 3, sc8 = (tid & 7) * 8; // 512 threads cover 64x64 in one shot

  const unsigned short* kptr =
      KVb + (size_t)(b * SS + srow) * (2 * DIM) + h * HD + sc8;
  const unsigned short* vptr = VTb + (size_t)(b * DIM + h * HD + srow) * SS + sc8;
  const size_t kstep = (size_t)64 * 2 * DIM;

  short8 kreg = *(const short8*)kptr;
  short8 vreg = *(const short8*)vptr;

  for (int kt = 0; kt <= ktmax; ++kt) {
    __syncthreads(); // prior-iter LDS readers done
    *(short8*)(Ks + srow * 72 + sc8) = kreg;
    *(short8*)(Vts + srow * 72 + sc8) = vreg;
    __syncthreads();
    if (kt < ktmax) { // prefetch next K/V tile (overlaps compute)
      kptr += kstep; vptr += 64;
      kreg = *(const short8*)kptr;
      vreg = *(const short8*)vptr;
    }

    const int k0g = kt * 64;
    if (k0g > qmaxw) continue; // whole tile masked for this wave (wave-uniform)
    const bool needmask = (k0g + 63 > qminw);

    f32x4 sacc[4]; // S^T: nt -> keys k0g+nt*16+quad*4+r, col q=ln
#pragma unroll
    for (int nt = 0; nt < 4; nt++) sacc[nt] = (f32x4){0.f, 0.f, 0.f, 0.f};
#pragma unroll
    for (int kc = 0; kc < 2; kc++) {
#pragma unroll
      for (int nt = 0; nt < 4; nt++) {
        if (k0g + nt * 16 > qmaxw) continue; // strip fully masked
        short8 kfrag = *(const short8*)(Ks + (nt * 16 + ln) * 72 + kc * 32 + quad * 8);
        sacc[nt] =
            __builtin_amdgcn_mfma_f32_16x16x32_bf16(kfrag, qfrag[kc], sacc[nt], 0, 0, 0);
      }
    }

    // Fixed-max softmax (elementwise); perm-packed b64 P-writes.
    const int qg = qminw + ln; // this thread's q column (global)
#pragma unroll
    for (int nt = 0; nt < 4; nt++) {
      float pe[4];
#pragma unroll
      for (int r = 0; r < 4; r++) {
        float p = __builtin_exp2f(sacc[nt][r] * SCALE_LOG2E);
        if (needmask && (k0g + nt * 16 + quad * 4 + r) > qg) p = 0.f;
        lpart += p;
        pe[r] = p;
      }
      uint2 pw;
      pw.x = pack_bf16_pair(pe[0], pe[1]);
      pw.y = pack_bf16_pair(pe[2], pe[3]);
      *(uint2*)(Pw + ln * 72 + nt * 16 + quad * 4) = pw;
    }

#pragma unroll
    for (int kc = 0; kc < 2; kc++) {
      if (k0g + kc * 32 > qmaxw) continue; // P chunk all zero
      short8 pfrag = *(const short8*)(Pw + ln * 72 + kc * 32 + quad * 8);
#pragma unroll
      for (int dt = 0; dt < 4; dt++) {
        short8 vfrag = *(const short8*)(Vts + (dt * 16 + ln) * 72 + kc * 32 + quad * 8);
        octx[dt] =
            __builtin_amdgcn_mfma_f32_16x16x32_bf16(pfrag, vfrag, octx[dt], 0, 0, 0);
      }
    }
  }

  // Denominator: reduce across the 4 quads, broadcast to owned rows.
  lpart += __shfl_xor(lpart, 16, 64);
  lpart += __shfl_xor(lpart, 32, 64);
  float linv[4];
#pragma unroll
  for (int r = 0; r < 4; r++) linv[r] = 1.f / __shfl(lpart, quad * 4 + r, 64);

  // Epilogue: normalize, stage 128x64 tile through smem, coalesced 16B stores.
  __syncthreads();
#pragma unroll
  for (int r = 0; r < 4; r++) {
#pragma unroll
    for (int dt = 0; dt < 4; dt++)
      smem[(wave * 16 + quad * 4 + r) * 72 + dt * 16 + ln] = f2b(octx[dt][r] * linv[r]);
  }
  __syncthreads();
#pragma unroll
  for (int t = 0; t < 2; ++t) {
    int idx = tid + t * 512;
    int row = idx >> 3, c = idx & 7;
    short8 v = *(const short8*)(smem + row * 72 + c * 8);
    *(short8*)(ctxB + (size_t)(b * SS + s0 + row) * DIM + h * HD + c * 8) = v;
  }
}

extern "C" void kernel_launch(void* const* d_in, const int* in_sizes, int n_in,
                              void* d_out, int out_size, void* d_ws, size_t ws_size,
                              hipStream_t stream) {
  const float* x     = (const float*)d_in[0];
  const float* w_kvc = (const float*)d_in[2];
  const float* b_kvc = (const float*)d_in[3];
  const float* w_kvu = (const float*)d_in[4];
  const float* b_kvu = (const float*)d_in[5];
  const float* w_qc  = (const float*)d_in[6];
  const float* b_qc  = (const float*)d_in[7];
  const float* w_qu  = (const float*)d_in[8];
  const float* b_qu  = (const float*)d_in[9];
  const float* w_o   = (const float*)d_in[10];
  const float* b_o   = (const float*)d_in[11];
  float* out = (float*)d_out;

  unsigned short* xb     = (unsigned short*)d_ws;          // [BS][DIM]; reused as VT
  unsigned short* wcatT  = xb + (size_t)BS * DIM;          // [NCAT][DIM]
  unsigned short* wkvuT  = wcatT + (size_t)NCAT * DIM;     // [2*DIM][LAT]
  unsigned short* wquT   = wkvuT + (size_t)LAT * 2 * DIM;  // [DIM][QR]
  unsigned short* woT    = wquT + (size_t)QR * DIM;        // [DIM][DIM]
  unsigned short* kvqlat = woT + (size_t)DIM * DIM;        // [BS][NCAT] (kv | q)
  unsigned short* kvup   = kvqlat + (size_t)BS * NCAT;     // [BS][2*DIM] (K | V)
  unsigned short* Qbuf   = kvup + (size_t)BS * 2 * DIM;    // [BS][DIM]
  unsigned short* ctx    = Qbuf + (size_t)BS * DIM;        // [BS][DIM]
  float* bias_cat        = (float*)(ctx + (size_t)BS * DIM); // [NCAT]

  cvt_x<<<(BS * DIM / 4 + 255) / 256, 256, 0, stream>>>(x, xb, BS * DIM / 4);
  prep_weights<<<481, 256, 0, stream>>>(w_kvc, w_qc, w_kvu, w_qu, w_o, b_kvc, b_qc,
                                        wcatT, wkvuT, wquT, woT, bias_cat);

  // fused stage-1: [kvlat | qlat] = x @ [w_kvc | w_qc]
  gemm_n64<<<dim3(BS / 64, NCAT / 64), 256, 0, stream>>>(xb, wcatT, bias_cat, kvqlat,
                                                         DIM, NCAT);
  // stage-2
  gemm_bf16<<<dim3(BS / 128, 2 * DIM / 128), 256, 0, stream>>>(
      kvqlat, wkvuT, b_kvu, nullptr, kvup, 2 * DIM, LAT, NCAT, 2 * DIM);
  unsigned short* VT = xb; // xb dead after stage-1
  transpose_v<<<dim3(SS / 64, DIM / 64, BB), 256, 0, stream>>>(kvup, VT);
  gemm_bf16<<<dim3(BS / 128, DIM / 128), 256, 0, stream>>>(
      kvqlat + LAT, wquT, b_qu, nullptr, Qbuf, DIM, QR, NCAT, DIM);
  attn_mfma<<<dim3(SS / 128, NH, BB), 512, 0, stream>>>(Qbuf, kvup, VT, ctx);
  gemm_bf16<<<dim3(BS / 128, DIM / 128), 256, 0, stream>>>(ctx, woT, b_o, out, nullptr,
                                                           DIM, DIM, DIM, DIM);
}